// Round 3
// baseline (768.895 us; speedup 1.0000x reference)
//
#include <hip/hip_runtime.h>
#include <math.h>

#define N_NODES 400000
#define N_EDGES 2400000
#define NPG 40
#define N_GRAPHS 10000
#define IN_F 30
#define H1 30
#define H2 10
#define OUTF 4
#define SCAN_NB 10   // ceil(10000/1024)

// ---------------- K1: integer degrees ----------------
__global__ void degree_kernel(const int* __restrict__ src, const int* __restrict__ dst,
                              int* __restrict__ deg_out, int* __restrict__ deg_in) {
    int i = blockIdx.x * blockDim.x + threadIdx.x;
    int stride = gridDim.x * blockDim.x;
    for (; i < N_EDGES; i += stride) {
        atomicAdd(&deg_out[src[i]], 1);
        atomicAdd(&deg_in[dst[i]], 1);
    }
}

// ---------------- K2: per-graph edge counts ----------------
__global__ void gsum_kernel(const int* __restrict__ deg_in, int* __restrict__ gsum) {
    int g = blockIdx.x * blockDim.x + threadIdx.x;
    if (g >= N_GRAPHS) return;
    int s = 0;
    #pragma unroll 8
    for (int k = 0; k < NPG; k++) s += deg_in[g * NPG + k];
    gsum[g] = s;
}

// ---------------- exclusive scan of gsum (10000) -> bin_start, gcursor ----------------
__global__ void scan1(const int* __restrict__ v_in, int* __restrict__ ex_out,
                      int* __restrict__ blk_sums, int n) {
    __shared__ int s[256];
    int t = threadIdx.x;
    int base = blockIdx.x * 1024 + t * 4;
    int v[4];
    #pragma unroll
    for (int k = 0; k < 4; k++) v[k] = (base + k < n) ? v_in[base + k] : 0;
    int tsum = v[0] + v[1] + v[2] + v[3];
    s[t] = tsum;
    __syncthreads();
    for (int o = 1; o < 256; o <<= 1) {
        int y = (t >= o) ? s[t - o] : 0;
        __syncthreads();
        s[t] += y;
        __syncthreads();
    }
    int run = s[t] - tsum;
    #pragma unroll
    for (int k = 0; k < 4; k++) {
        if (base + k < n) ex_out[base + k] = run;
        run += v[k];
    }
    if (t == 255) blk_sums[blockIdx.x] = s[255];
}

__global__ void scan2(const int* __restrict__ blk_sums, int* __restrict__ blk_off, int nb) {
    if (threadIdx.x == 0) {
        int run = 0;
        for (int i = 0; i < nb; i++) { blk_off[i] = run; run += blk_sums[i]; }
    }
}

__global__ void scan3(int* __restrict__ bin_start, int* __restrict__ gcursor,
                      const int* __restrict__ blk_off, int n) {
    int t = threadIdx.x;
    int off = blk_off[blockIdx.x];
    int base = blockIdx.x * 1024 + t * 4;
    #pragma unroll
    for (int k = 0; k < 4; k++) {
        int i = base + k;
        if (i < n) {
            int r = bin_start[i] + off;
            bin_start[i] = r;
            gcursor[i] = r;
        }
    }
}

// ---------------- K3: bin edges by dst graph, packed (src<<6)|dst_local ----------------
__global__ void bin_fill(const int* __restrict__ src, const int* __restrict__ dst,
                         int* __restrict__ gcursor, unsigned* __restrict__ binned) {
    int i = blockIdx.x * blockDim.x + threadIdx.x;
    int stride = gridDim.x * blockDim.x;
    for (; i < N_EDGES; i += stride) {
        int d = dst[i];
        int g = d / NPG;                 // magic-mul division by constant
        int dl = d - g * NPG;
        int pos = atomicAdd(&gcursor[g], 1);
        binned[pos] = ((unsigned)src[i] << 6) | (unsigned)dl;
    }
}

// ---------------- K4: fused aggregate(x*ns) -> @W*nd+b -> max-pool -> MLP -> sigmoid ----
__global__ __launch_bounds__(256) void agg_pool_mlp(
    const float* __restrict__ feat, const int* __restrict__ deg_out,
    const int* __restrict__ deg_in, const int* __restrict__ bin_start,
    const int* __restrict__ gsum, const unsigned* __restrict__ binned,
    const float* __restrict__ W, const float* __restrict__ b,
    const float* __restrict__ W2, const float* __restrict__ b2,
    const float* __restrict__ W3, const float* __restrict__ b3,
    float* __restrict__ out) {
    int g = blockIdx.x;
    int t = threadIdx.x;     // 256
    int f = t & 31;          // feature lane
    int hw = t >> 5;         // half-wave 0..7
    __shared__ float acc[NPG][33];   // +33 pad: bank = (dl+f)%32, spreads dst rows
    __shared__ float sW[IN_F * H1];
    __shared__ float smax[8][32];
    __shared__ float z[H2];

    for (int i = t; i < NPG * 33; i += 256) ((float*)acc)[i] = 0.f;
    for (int i = t; i < IN_F * H1; i += 256) sW[i] = W[i];
    __syncthreads();

    int beg = bin_start[g];
    int cnt = gsum[g];
    for (int e = hw; e < cnt; e += 8) {
        unsigned p = binned[beg + e];
        int s = (int)(p >> 6);
        int dl = (int)(p & 63u);
        float ns = rsqrtf(fmaxf((float)deg_out[s], 1.0f));
        if (f < IN_F) {
            float v = feat[(size_t)s * IN_F + f] * ns;
            atomicAdd(&acc[dl][f], v);
        }
    }
    __syncthreads();

    float m = -INFINITY;
    for (int n = hw; n < NPG; n += 8) {
        float nd = rsqrtf(fmaxf((float)deg_in[g * NPG + n], 1.0f));
        if (f < H1) {
            float s = 0.f;
            #pragma unroll
            for (int k = 0; k < IN_F; k++) s += acc[n][k] * sW[k * H1 + f];
            m = fmaxf(m, s * nd + b[f]);
        }
    }
    smax[hw][f] = m;
    __syncthreads();
    if (t < 32) {
        float mm = smax[0][t];
        #pragma unroll
        for (int k = 1; k < 8; k++) mm = fmaxf(mm, smax[k][t]);
        smax[0][t] = mm;   // pooled[f], valid for f < 30
    }
    __syncthreads();
    if (t < H2) {
        float s2 = b2[t];
        #pragma unroll
        for (int k = 0; k < H1; k++) s2 += smax[0][k] * W2[k * H2 + t];
        z[t] = fmaxf(s2, 0.f);
    }
    __syncthreads();
    if (t < OUTF) {
        float s3 = b3[t];
        #pragma unroll
        for (int k = 0; k < H2; k++) s3 += z[k] * W3[k * OUTF + t];
        out[g * OUTF + t] = 1.f / (1.f + expf(-s3));
    }
}

extern "C" void kernel_launch(void* const* d_in, const int* in_sizes, int n_in,
                              void* d_out, int out_size, void* d_ws, size_t ws_size,
                              hipStream_t stream) {
    const float* feat = (const float*)d_in[0];
    const int*   src  = (const int*)d_in[1];
    const int*   dst  = (const int*)d_in[2];
    const float* W  = (const float*)d_in[5];
    const float* b  = (const float*)d_in[6];
    const float* W2 = (const float*)d_in[7];
    const float* b2 = (const float*)d_in[8];
    const float* W3 = (const float*)d_in[9];
    const float* b3 = (const float*)d_in[10];
    float* out = (float*)d_out;

    char* ws = (char*)d_ws;
    int* deg_out   = (int*)ws;                   // 400000
    int* deg_in    = deg_out + N_NODES;          // 400000
    int* gsum      = deg_in + N_NODES;           // 10240 (pad)
    int* bin_start = gsum + 10240;               // 10240
    int* gcursor   = bin_start + 10240;          // 10240
    int* blk_sums  = gcursor + 10240;            // 64
    int* blk_off   = blk_sums + 64;              // 64
    unsigned* binned = (unsigned*)(blk_off + 64);  // 2400000

    hipMemsetAsync(deg_out, 0, sizeof(int) * 2 * N_NODES, stream);

    degree_kernel<<<2048, 256, 0, stream>>>(src, dst, deg_out, deg_in);

    gsum_kernel<<<(N_GRAPHS + 255) / 256, 256, 0, stream>>>(deg_in, gsum);

    scan1<<<SCAN_NB, 256, 0, stream>>>(gsum, bin_start, blk_sums, N_GRAPHS);
    scan2<<<1, 64, 0, stream>>>(blk_sums, blk_off, SCAN_NB);
    scan3<<<SCAN_NB, 256, 0, stream>>>(bin_start, gcursor, blk_off, N_GRAPHS);

    bin_fill<<<2048, 256, 0, stream>>>(src, dst, gcursor, binned);

    agg_pool_mlp<<<N_GRAPHS, 256, 0, stream>>>(feat, deg_out, deg_in, bin_start, gsum,
                                               binned, W, b, W2, b2, W3, b3, out);
}